// Round 6
// baseline (1199.491 us; speedup 1.0000x reference)
//
#include <hip/hip_runtime.h>
#include <cstdint>
#include <cstddef>

typedef _Float16 half8 __attribute__((ext_vector_type(8)));
typedef _Float16 half4v __attribute__((ext_vector_type(4)));
typedef float f32x4 __attribute__((ext_vector_type(4)));

#define NCOL 512   // 2*M interleaved (re,im)
#define KY 256     // 2*N interleaved

__device__ __forceinline__ float shrinkf(float v, float eta) {
  float a = fabsf(v) - eta;           // LAMBD = 1.0
  return a > 0.0f ? copysignf(a, v) : 0.0f;
}

// ---------- table builders ----------
__global__ void build_wa(const float* __restrict__ A, _Float16* __restrict__ Wa) {
  int idx = blockIdx.x * 256 + threadIdx.x;     // 131072
  int n = idx >> 8, k = idx & 255;
  int p = n >> 1, c = n & 1, q = k >> 1, d = k & 1;
  const float* A0 = A;                // (256,128)
  const float* A1 = A + 256 * 128;
  float v;
  if (c == 0) v = (d == 0) ? A0[p * 128 + q] : -A1[p * 128 + q];
  else        v = (d == 0) ? A1[p * 128 + q] :  A0[p * 128 + q];
  Wa[idx] = (_Float16)v;
}

__global__ void build_wb(const float* __restrict__ B, _Float16* __restrict__ Wb) {
  int idx = blockIdx.x * 256 + threadIdx.x;     // 262144
  int n = idx >> 9, k = idx & 511;
  int p = n >> 1, c = n & 1, q = k >> 1, d = k & 1;
  const float* B0 = B;                // (256,256)
  const float* B1 = B + 256 * 256;
  float v;
  if (c == 0) v = (d == 0) ?  B0[p * 256 + q] : -B1[p * 256 + q];
  else        v = (d == 0) ?  B1[p * 256 + q] :  B0[p * 256 + q];
  Wb[idx] = (_Float16)v;
}

// ---------- fused LISTA chain ----------
// Block = 64 batch rows, 512 threads / 8 waves; wave w owns features
// [w*64, w*64+64). Per t: u = realify(B)@x (MFMA, Wb from L2), then
//   x_next = shrink(x_old + g*(Ay - u), eta)
// x in LDS [64][512] fp16, 16B-chunk XOR swizzle. Ay in registers (32 VGPR).
// GEMM inner loop: explicit register-slot software pipeline —
//   afP[4] (Wb from L2, prefetch distance 2), bfP[2] (x from LDS, distance 1).
// Named slots force counted vmcnt/lgkmcnt waits (never a full drain) and
// structurally cap in-flight loads (no hoist-spill).
__global__ __launch_bounds__(512, 2) void lista_fused(
    const float* __restrict__ y,
    const _Float16* __restrict__ Wa,
    const _Float16* __restrict__ Wb,
    float* __restrict__ out,
    const float* __restrict__ gammas,
    const float* __restrict__ etas) {
  __shared__ __align__(16) _Float16 xlds[64 * 512];   // 64 KB

  const int tid  = threadIdx.x;
  const int l16  = tid & 15;
  const int quad = (tid >> 4) & 3;
  const int wave = tid >> 6;          // 0..7 feature slice
  const int l7   = l16 & 7;
  const int b0   = blockIdx.x << 6;   // batch base
  const int fb   = wave << 6;         // feature base (64 per wave)
  const int fc   = wave << 3;         // feature base in 8-half chunks

  f32x4 acc[4][4];
#pragma unroll
  for (int i = 0; i < 4; ++i)
#pragma unroll
    for (int j = 0; j < 4; ++j) acc[i][j] = {0.f, 0.f, 0.f, 0.f};

  // ---- prologue: acc = Ay tile = Wa(feat,K) @ y^T(K,batch), K=256 ----
#pragma unroll 1
  for (int kt = 0; kt < 4; ++kt) {
#pragma unroll
    for (int ks = 0; ks < 2; ++ks) {
      const int k0 = kt * 64 + ks * 32 + quad * 8;
      half8 bf[4];
#pragma unroll
      for (int j = 0; j < 4; ++j) {
        const float* yp = y + (size_t)(b0 + j * 16 + l16) * KY + k0;
        f32x4 a = *(const f32x4*)yp;
        f32x4 b = *(const f32x4*)(yp + 4);
        half8 h;
        h[0] = (_Float16)a.x; h[1] = (_Float16)a.y;
        h[2] = (_Float16)a.z; h[3] = (_Float16)a.w;
        h[4] = (_Float16)b.x; h[5] = (_Float16)b.y;
        h[6] = (_Float16)b.z; h[7] = (_Float16)b.w;
        bf[j] = h;
      }
      half8 af[4];
#pragma unroll
      for (int i = 0; i < 4; ++i)
        af[i] = *(const half8*)(Wa + (size_t)(fb + i * 16 + l16) * KY + k0);
#pragma unroll
      for (int i = 0; i < 4; ++i)
#pragma unroll
        for (int j = 0; j < 4; ++j)
          acc[i][j] = __builtin_amdgcn_mfma_f32_16x16x32_f16(
              af[i], bf[j], acc[i][j], 0, 0, 0);
    }
  }

  // epilogue 0: Ay -> registers (fp16 packed); x0 = shrink(g0*Ay) -> LDS
  const float g0 = gammas[0], e0 = etas[0];
  half4v ayv[4][4];
#pragma unroll
  for (int i = 0; i < 4; ++i) {
    const int cw = ((fc + i * 2 + (quad >> 1)) ^ l7) * 8 + (quad & 1) * 4;
#pragma unroll
    for (int j = 0; j < 4; ++j) {
      f32x4 v = acc[i][j];
      half4v a4 = {(_Float16)v.x, (_Float16)v.y, (_Float16)v.z, (_Float16)v.w};
      ayv[i][j] = a4;
      half4v x0 = {(_Float16)shrinkf(g0 * v.x, e0), (_Float16)shrinkf(g0 * v.y, e0),
                   (_Float16)shrinkf(g0 * v.z, e0), (_Float16)shrinkf(g0 * v.w, e0)};
      *(half4v*)(xlds + (j * 16 + l16) * NCOL + cw) = x0;
    }
  }

  // wave-constant bases for the pipelined GEMM
  const _Float16* wb0 = Wb + (size_t)(fb +  0 + l16) * NCOL + quad * 8;
  const _Float16* wb1 = Wb + (size_t)(fb + 16 + l16) * NCOL + quad * 8;
  const _Float16* wb2 = Wb + (size_t)(fb + 32 + l16) * NCOL + quad * 8;
  const _Float16* wb3 = Wb + (size_t)(fb + 48 + l16) * NCOL + quad * 8;
  const _Float16* xb0 = xlds + (size_t)( 0 + l16) * NCOL;
  const _Float16* xb1 = xlds + (size_t)(16 + l16) * NCOL;
  const _Float16* xb2 = xlds + (size_t)(32 + l16) * NCOL;
  const _Float16* xb3 = xlds + (size_t)(48 + l16) * NCOL;
  const int bc0 = (quad ^ l7) * 8;        // ks=0 chunk byte-offset (halves)
  const int bc1 = bc0 ^ 32;               // ks=1: chunk ^= 4 -> halves ^= 32

  // ---- main loop: x = shrink(x + g*(Ay - Wb@x)), t = 1..10 ----
#pragma unroll 1
  for (int t = 1; t <= 10; ++t) {
    __syncthreads();                  // x writes visible to all waves

#pragma unroll
    for (int i = 0; i < 4; ++i)
#pragma unroll
      for (int j = 0; j < 4; ++j) acc[i][j] = {0.f, 0.f, 0.f, 0.f};

    half8 afP[4][4];
    half8 bfP[2][4];

#define PFA(s) {                                                         \
    const int wk = (s) * 32;                                             \
    afP[(s) & 3][0] = *(const half8*)(wb0 + wk);                         \
    afP[(s) & 3][1] = *(const half8*)(wb1 + wk);                         \
    afP[(s) & 3][2] = *(const half8*)(wb2 + wk);                         \
    afP[(s) & 3][3] = *(const half8*)(wb3 + wk); }
#define PFB(s) {                                                         \
    const int kb = ((s) >> 1) * 64 + (((s) & 1) ? bc1 : bc0);            \
    bfP[(s) & 1][0] = *(const half8*)(xb0 + kb);                         \
    bfP[(s) & 1][1] = *(const half8*)(xb1 + kb);                         \
    bfP[(s) & 1][2] = *(const half8*)(xb2 + kb);                         \
    bfP[(s) & 1][3] = *(const half8*)(xb3 + kb); }
#define MM(s) {                                                          \
    _Pragma("unroll")                                                    \
    for (int i = 0; i < 4; ++i)                                          \
      _Pragma("unroll")                                                  \
      for (int j = 0; j < 4; ++j)                                        \
        acc[i][j] = __builtin_amdgcn_mfma_f32_16x16x32_f16(              \
            afP[(s) & 3][i], bfP[(s) & 1][j], acc[i][j], 0, 0, 0); }

    PFA(0) PFA(1) PFB(0)
    PFA(2)  PFB(1)  MM(0)
    PFA(3)  PFB(2)  MM(1)
    PFA(4)  PFB(3)  MM(2)
    PFA(5)  PFB(4)  MM(3)
    PFA(6)  PFB(5)  MM(4)
    PFA(7)  PFB(6)  MM(5)
    PFA(8)  PFB(7)  MM(6)
    PFA(9)  PFB(8)  MM(7)
    PFA(10) PFB(9)  MM(8)
    PFA(11) PFB(10) MM(9)
    PFA(12) PFB(11) MM(10)
    PFA(13) PFB(12) MM(11)
    PFA(14) PFB(13) MM(12)
    PFA(15) PFB(14) MM(13)
            PFB(15) MM(14)
                    MM(15)
#undef PFA
#undef PFB
#undef MM

    const float g = gammas[t], eta = etas[t];
    __syncthreads();                  // all reads of x done before overwrite

    if (t < 10) {
#pragma unroll
      for (int i = 0; i < 4; ++i) {
        const int cw = ((fc + i * 2 + (quad >> 1)) ^ l7) * 8 + (quad & 1) * 4;
#pragma unroll
        for (int j = 0; j < 4; ++j) {
          half4v a4 = ayv[i][j];
          half4v xo = *(const half4v*)(xlds + (j * 16 + l16) * NCOL + cw);
          f32x4 u = acc[i][j];
          half4v xn;
#pragma unroll
          for (int r = 0; r < 4; ++r) {
            float val = fmaf(g, (float)a4[r] - u[r], (float)xo[r]);
            xn[r] = (_Float16)shrinkf(val, eta);
          }
          *(half4v*)(xlds + (j * 16 + l16) * NCOL + cw) = xn;
        }
      }
    } else {
#pragma unroll
      for (int i = 0; i < 4; ++i) {
        const int cw = ((fc + i * 2 + (quad >> 1)) ^ l7) * 8 + (quad & 1) * 4;
#pragma unroll
        for (int j = 0; j < 4; ++j) {
          half4v a4 = ayv[i][j];
          half4v xo = *(const half4v*)(xlds + (j * 16 + l16) * NCOL + cw);
          f32x4 u = acc[i][j];
          f32x4 o;
#pragma unroll
          for (int r = 0; r < 4; ++r) {
            float val = fmaf(g, (float)a4[r] - u[r], (float)xo[r]);
            o[r] = shrinkf(val, eta);
          }
          *(f32x4*)(out + (size_t)(b0 + j * 16 + l16) * NCOL + fb + i * 16 + quad * 4) = o;
        }
      }
    }
  }
}

extern "C" void kernel_launch(void* const* d_in, const int* in_sizes, int n_in,
                              void* d_out, int out_size, void* d_ws, size_t ws_size,
                              hipStream_t stream) {
  const float* y      = (const float*)d_in[0];
  const float* A      = (const float*)d_in[1];
  const float* B      = (const float*)d_in[2];
  const float* etas   = (const float*)d_in[3];
  const float* gammas = (const float*)d_in[4];

  char* ws = (char*)d_ws;
  _Float16* Wa = (_Float16*)ws;                       // 512*256*2 = 256 KB
  _Float16* Wb = (_Float16*)(ws + 262144);            // 512*512*2 = 512 KB

  hipLaunchKernelGGL(build_wa, dim3(512), dim3(256), 0, stream, A, Wa);
  hipLaunchKernelGGL(build_wb, dim3(1024), dim3(256), 0, stream, B, Wb);
  hipLaunchKernelGGL(lista_fused, dim3(1024), dim3(512), 0, stream,
                     y, Wa, Wb, (float*)d_out, gammas, etas);
}